// Round 12
// baseline (113.582 us; speedup 1.0000x reference)
//
#include <hip/hip_runtime.h>
#include <math.h>

// ============================================================================
// ROUND 11/12 = TIMING PROBE. Kernel is BIT-IDENTICAL to round 10; kernel_launch
// invokes it 4x back-to-back (idempotent: same output each time). Purpose:
// dur_us = fixed_overhead + k_cold + 3*k_warm  ->  separates harness fixed
// overhead from kernel-proper time, which is invisible in top-5 rocprof
// (always below the ~44us ws-poison fill cut). Next round reverts to 1x.
// ============================================================================

#define T_LEN  131072
#define CHUNK  4096             // outputs per block
#define HPAD   4096             // compile-time history window (alpha^HPAD <= 1e-8 for alpha<=0.9955)
#define WIN    (CHUNK + HPAD)   // 8192 samples per block
#define EPT    32               // samples per thread strip
#define NT     (WIN / EPT)      // 256 threads (4 waves)
#define NWAVE  (NT / 64)        // 4
#define OUT_T0 (HPAD / EPT)     // 128: out thread tid>=128 owns its own strip
#define NUNIT  (WIN / 4)        // 2048 float4 units
#define HUNIT  (HPAD / 4)       // 1024

__device__ __forceinline__ int swz(int u) { return u ^ ((u >> 3) & 7); }

__global__ __launch_bounds__(NT) void iir_env_kernel(
    const float* __restrict__ signal,   // (32, 2, 131072)
    const float* __restrict__ z_alpha,  // (32, 1)
    float* __restrict__ out)            // (32, 131072)
{
    __shared__ float4 buf[NUNIT];       // 32 KiB energy / output staging
    __shared__ float  carr[NWAVE];      // wave carries

    const int tid  = threadIdx.x;
    const int lane = tid & 63;
    const int wid  = tid >> 6;
    const int row  = blockIdx.x >> 5;   // 32 chunks per row
    const int chk  = blockIdx.x & 31;

    // ---- alpha + derived powers (double, once per thread) ----
    double zd = (double)z_alpha[row];
    double ad = 1.0 / (1.0 + exp(-zd));
    ad = ad < 1e-5 ? 1e-5 : (ad > 1.0 - 1e-5 ? 1.0 - 1e-5 : ad);
    const float a     = (float)ad;
    const float onema = (float)(1.0 - ad);

    // runtime skip: history older than H_rt (alpha^H_rt = 1e-8) is irrelevant
    const double H_rt = 18.42 / (-log(ad));
    int u_cut = HUNIT - ((int)(H_rt * 0.25) + 1);   // in float4 units
    if (u_cut < 0) u_cut = 0;
    if (chk == 0) u_cut = HUNIT;                    // no negative-time signal

    double p = ad;
    p = p*p; p = p*p; p = p*p; p = p*p; p = p*p;                 // a^32
    const float A32 = (float)p;
    p = p*p; p = p*p; p = p*p; p = p*p; p = p*p; p = p*p;        // a^2048
    const float A2048 = (float)p;

    // ---- phase 1: coalesced loads -> energy -> swizzled LDS ----
    const long gofs = (long)chk * CHUNK - HPAD;
    const float* p0 = signal + (size_t)row * 2 * T_LEN;
    const float* p1 = p0 + T_LEN;
    #pragma unroll
    for (int k = 0; k < 8; ++k) {
        const int u = tid + NT * k;
        float4 e4 = make_float4(0.f, 0.f, 0.f, 0.f);
        if (u >= u_cut) {
            const long g = gofs + 4l * u;
            const float4 x0 = *reinterpret_cast<const float4*>(p0 + g);
            const float4 x1 = *reinterpret_cast<const float4*>(p1 + g);
            e4.x = 0.5f * fmaf(x0.x, x0.x, x1.x * x1.x);
            e4.y = 0.5f * fmaf(x0.y, x0.y, x1.y * x1.y);
            e4.z = 0.5f * fmaf(x0.z, x0.z, x1.z * x1.z);
            e4.w = 0.5f * fmaf(x0.w, x0.w, x1.w * x1.w);
        }
        buf[swz(u)] = e4;
    }
    __syncthreads();

    // ---- phase 2: read own 32-sample strip from LDS ----
    float e[EPT];
    #pragma unroll
    for (int j = 0; j < 8; ++j) {
        const float4 v4 = buf[swz(8 * tid + j)];
        e[4*j+0] = v4.x; e[4*j+1] = v4.y; e[4*j+2] = v4.z; e[4*j+3] = v4.w;
    }

    // ---- phase 3: local scan + wave Kogge-Stone + wave carries ----
    float s0 = 0.0f;
    #pragma unroll
    for (int i = 0; i < EPT; ++i) s0 = fmaf(a, s0, onema * e[i]);

    float v = s0;
    float m = A32;
    #pragma unroll
    for (int off = 1; off < 64; off <<= 1) {
        float up = __shfl_up(v, off, 64);
        if (lane >= off) v = fmaf(m, up, v);
        m = m * m;
    }
    if (lane == 63) carr[wid] = v;
    __syncthreads();

    // ---- phase 4: block prefix, rescan + log, stage to LDS ----
    float P = 0.0f;
    for (int w = 0; w < wid; ++w) P = fmaf(A2048, P, carr[w]);

    const float iprev = __shfl_up(v, 1, 64);
    float apl = 1.0f, bb = A32;
    #pragma unroll
    for (int b = 0; b < 6; ++b) { if (lane & (1 << b)) apl *= bb; bb = bb * bb; }
    const float E = fmaf(apl, P, (lane > 0) ? iprev : 0.0f);

    if (tid >= OUT_T0) {
        const int rr = tid - OUT_T0;
        float st = E;
        #pragma unroll
        for (int j = 0; j < 8; ++j) {
            float4 o;
            float* ov = &o.x;
            #pragma unroll
            for (int c = 0; c < 4; ++c) {
                st = fmaf(a, st, onema * e[4*j + c]);
                ov[c] = __logf(fmaxf(st, 0.0f) + 1e-5f);
            }
            buf[swz(8 * rr + j)] = o;
        }
    }
    __syncthreads();

    // ---- phase 5: coalesced float4 stores ----
    float* po = out + (size_t)row * T_LEN + chk * CHUNK;
    #pragma unroll
    for (int k = 0; k < 4; ++k) {
        const int uo = tid + NT * k;
        *reinterpret_cast<float4*>(po + 4 * uo) = buf[swz(uo)];
    }
}

extern "C" void kernel_launch(void* const* d_in, const int* in_sizes, int n_in,
                              void* d_out, int out_size, void* d_ws, size_t ws_size,
                              hipStream_t stream) {
    const float* signal  = (const float*)d_in[0];
    const float* z_alpha = (const float*)d_in[1];
    float* out = (float*)d_out;
    dim3 grid(32 * (T_LEN / CHUNK));    // 1024 blocks = 4 per CU
    dim3 block(NT);
    // PROBE: 4 idempotent launches. dur_us = fixed + k_cold + 3*k_warm.
    for (int rep = 0; rep < 4; ++rep) {
        hipLaunchKernelGGL(iir_env_kernel, grid, block, 0, stream, signal, z_alpha, out);
    }
}

// Round 13
// 81.301 us; speedup vs baseline: 1.3971x; 1.3971x over previous
//
#include <hip/hip_runtime.h>
#include <math.h>

// Reverted to the single-launch round-10 kernel (probe done: k_warm ~= 11.1us,
// fixed harness overhead ~= 69us of the ~80us dur_us; kernel is at ~76% of its
// 8.4us memory-traffic floor).

#define T_LEN  131072
#define CHUNK  4096             // outputs per block
#define HPAD   4096             // compile-time history window (alpha^HPAD <= 1e-8 for alpha<=0.9955)
#define WIN    (CHUNK + HPAD)   // 8192 samples per block
#define EPT    32               // samples per thread strip
#define NT     (WIN / EPT)      // 256 threads (4 waves)
#define NWAVE  (NT / 64)        // 4
#define OUT_T0 (HPAD / EPT)     // 128: out thread tid>=128 owns its own strip
#define NUNIT  (WIN / 4)        // 2048 float4 units
#define HUNIT  (HPAD / 4)       // 1024

__device__ __forceinline__ int swz(int u) { return u ^ ((u >> 3) & 7); }

__global__ __launch_bounds__(NT) void iir_env_kernel(
    const float* __restrict__ signal,   // (32, 2, 131072)
    const float* __restrict__ z_alpha,  // (32, 1)
    float* __restrict__ out)            // (32, 131072)
{
    __shared__ float4 buf[NUNIT];       // 32 KiB energy / output staging
    __shared__ float  carr[NWAVE];      // wave carries

    const int tid  = threadIdx.x;
    const int lane = tid & 63;
    const int wid  = tid >> 6;
    const int row  = blockIdx.x >> 5;   // 32 chunks per row
    const int chk  = blockIdx.x & 31;

    // ---- alpha + derived powers (double, once per thread) ----
    double zd = (double)z_alpha[row];
    double ad = 1.0 / (1.0 + exp(-zd));
    ad = ad < 1e-5 ? 1e-5 : (ad > 1.0 - 1e-5 ? 1.0 - 1e-5 : ad);
    const float a     = (float)ad;
    const float onema = (float)(1.0 - ad);

    // runtime skip: history older than H_rt (alpha^H_rt = 1e-8) is irrelevant
    const double H_rt = 18.42 / (-log(ad));
    int u_cut = HUNIT - ((int)(H_rt * 0.25) + 1);   // in float4 units
    if (u_cut < 0) u_cut = 0;
    if (chk == 0) u_cut = HUNIT;                    // no negative-time signal

    double p = ad;
    p = p*p; p = p*p; p = p*p; p = p*p; p = p*p;                 // a^32
    const float A32 = (float)p;
    p = p*p; p = p*p; p = p*p; p = p*p; p = p*p; p = p*p;        // a^2048
    const float A2048 = (float)p;

    // ---- phase 1: coalesced loads -> energy -> swizzled LDS ----
    const long gofs = (long)chk * CHUNK - HPAD;
    const float* p0 = signal + (size_t)row * 2 * T_LEN;
    const float* p1 = p0 + T_LEN;
    #pragma unroll
    for (int k = 0; k < 8; ++k) {
        const int u = tid + NT * k;
        float4 e4 = make_float4(0.f, 0.f, 0.f, 0.f);
        if (u >= u_cut) {
            const long g = gofs + 4l * u;
            const float4 x0 = *reinterpret_cast<const float4*>(p0 + g);
            const float4 x1 = *reinterpret_cast<const float4*>(p1 + g);
            e4.x = 0.5f * fmaf(x0.x, x0.x, x1.x * x1.x);
            e4.y = 0.5f * fmaf(x0.y, x0.y, x1.y * x1.y);
            e4.z = 0.5f * fmaf(x0.z, x0.z, x1.z * x1.z);
            e4.w = 0.5f * fmaf(x0.w, x0.w, x1.w * x1.w);
        }
        buf[swz(u)] = e4;
    }
    __syncthreads();

    // ---- phase 2: read own 32-sample strip from LDS ----
    float e[EPT];
    #pragma unroll
    for (int j = 0; j < 8; ++j) {
        const float4 v4 = buf[swz(8 * tid + j)];
        e[4*j+0] = v4.x; e[4*j+1] = v4.y; e[4*j+2] = v4.z; e[4*j+3] = v4.w;
    }

    // ---- phase 3: local scan + wave Kogge-Stone + wave carries ----
    float s0 = 0.0f;
    #pragma unroll
    for (int i = 0; i < EPT; ++i) s0 = fmaf(a, s0, onema * e[i]);

    float v = s0;
    float m = A32;
    #pragma unroll
    for (int off = 1; off < 64; off <<= 1) {
        float up = __shfl_up(v, off, 64);
        if (lane >= off) v = fmaf(m, up, v);
        m = m * m;
    }
    if (lane == 63) carr[wid] = v;
    __syncthreads();

    // ---- phase 4: block prefix, rescan + log, stage to LDS ----
    float P = 0.0f;
    for (int w = 0; w < wid; ++w) P = fmaf(A2048, P, carr[w]);

    const float iprev = __shfl_up(v, 1, 64);
    float apl = 1.0f, bb = A32;
    #pragma unroll
    for (int b = 0; b < 6; ++b) { if (lane & (1 << b)) apl *= bb; bb = bb * bb; }
    const float E = fmaf(apl, P, (lane > 0) ? iprev : 0.0f);

    if (tid >= OUT_T0) {
        const int rr = tid - OUT_T0;
        float st = E;
        #pragma unroll
        for (int j = 0; j < 8; ++j) {
            float4 o;
            float* ov = &o.x;
            #pragma unroll
            for (int c = 0; c < 4; ++c) {
                st = fmaf(a, st, onema * e[4*j + c]);
                ov[c] = __logf(fmaxf(st, 0.0f) + 1e-5f);
            }
            buf[swz(8 * rr + j)] = o;
        }
    }
    __syncthreads();

    // ---- phase 5: coalesced float4 stores ----
    float* po = out + (size_t)row * T_LEN + chk * CHUNK;
    #pragma unroll
    for (int k = 0; k < 4; ++k) {
        const int uo = tid + NT * k;
        *reinterpret_cast<float4*>(po + 4 * uo) = buf[swz(uo)];
    }
}

extern "C" void kernel_launch(void* const* d_in, const int* in_sizes, int n_in,
                              void* d_out, int out_size, void* d_ws, size_t ws_size,
                              hipStream_t stream) {
    const float* signal  = (const float*)d_in[0];
    const float* z_alpha = (const float*)d_in[1];
    float* out = (float*)d_out;
    dim3 grid(32 * (T_LEN / CHUNK));    // 1024 blocks = 4 per CU
    dim3 block(NT);
    hipLaunchKernelGGL(iir_env_kernel, grid, block, 0, stream, signal, z_alpha, out);
}